// Round 13
// baseline (356.531 us; speedup 1.0000x reference)
//
#include <hip/hip_runtime.h>

typedef unsigned long long u64;
typedef unsigned short ushort_t;
typedef unsigned int uint32;

#define NNODES 12288
#define WORDS 192    // 12288 / 64 bits per row
#define ELLW 256     // max neighbors per row (avg ~64)
#define ZROW NNODES  // zeroed pad row index
#define CHROWS (NNODES + 8)          // rows per chunk incl. pad
#define CHSZS (CHROWS * 32)          // SHORTS per 32-col bf16 chunk (8 chunks)

typedef __attribute__((ext_vector_type(8))) short short8_t;   // 8 bf16 (4 VGPRs)
typedef __attribute__((ext_vector_type(4))) float f32x4;      // MFMA C/D frag

// ---- bf16 split helpers (RNE) ----
__device__ __forceinline__ ushort_t f2bf(float f) {
    uint32 u = __float_as_uint(f);
    return (ushort_t)((u + 0x7fffu + ((u >> 16) & 1u)) >> 16);
}
__device__ __forceinline__ float bf2f(ushort_t h) {
    return __uint_as_float(((uint32)h) << 16);
}

// ---------------- adjacency build: bitmask M[s][d], MT[d][s] ----------------
__global__ void build_mask_kernel(const int* __restrict__ ei, u64* __restrict__ M,
                                  u64* __restrict__ MT, int E) {
    int e = blockIdx.x * blockDim.x + threadIdx.x;
    if (e >= E) return;
    int s = ei[e];
    int d = ei[E + e];
    atomicOr(&M[(size_t)s * WORDS + (d >> 6)], 1ull << (d & 63));
    atomicOr(&MT[(size_t)d * WORDS + (s >> 6)], 1ull << (s & 63));
}

// ---------------- bitmask -> u16 ELL (padded to x8 with ZROW) ----------------
__global__ __launch_bounds__(256) void ell_fill_kernel(
        const u64* __restrict__ M, const u64* __restrict__ MT,
        ushort_t* __restrict__ ell, int* __restrict__ cnt, float* __restrict__ dinv) {
    int row = blockIdx.x * 4 + (threadIdx.x >> 6);
    int lane = threadIdx.x & 63;
    const u64* rM  = M  + (size_t)row * WORDS;
    const u64* rMT = MT + (size_t)row * WORDS;
    u64 wm[3], wt[3];
    int pm = 0, pt = 0;
    #pragma unroll
    for (int k = 0; k < 3; ++k) {
        wm[k] = rM[lane + 64 * k];  pm += __popcll(wm[k]);
        wt[k] = rMT[lane + 64 * k]; pt += __popcll(wt[k]);
    }
    int inclM = pm, inclT = pt;
    #pragma unroll
    for (int off = 1; off < 64; off <<= 1) {
        int ym = __shfl_up(inclM, off, 64);
        int yt = __shfl_up(inclT, off, 64);
        if (lane >= off) { inclM += ym; inclT += yt; }
    }
    int exclM = inclM - pm;
    int exclT = inclT - pt;
    int totM = __shfl(inclM, 63, 64);
    int totT = __shfl(inclT, 63, 64);
    ushort_t* out = ell + (size_t)row * ELLW;
    int pos = exclM;
    #pragma unroll
    for (int k = 0; k < 3; ++k) {
        u64 bits = wm[k];
        int base = (lane + 64 * k) << 6;
        while (bits) { out[pos++] = (ushort_t)(base + __builtin_ctzll(bits)); bits &= bits - 1; }
    }
    pos = totM + exclT;
    #pragma unroll
    for (int k = 0; k < 3; ++k) {
        u64 bits = wt[k];
        int base = (lane + 64 * k) << 6;
        while (bits) { out[pos++] = (ushort_t)(base + __builtin_ctzll(bits)); bits &= bits - 1; }
    }
    if (lane == 0) {
        int n = totM + totT;
        int np = (n + 7) & ~7;
        for (int p = n; p < np; ++p) out[p] = (ushort_t)ZROW;
        cnt[row] = n;
        dinv[row] = 1.0f / ((float)n + 1e-8f);
    }
}

// zero the 8 pad rows of each of the 8 chunks (bf16 hi and lo arrays)
__global__ void clear_pad_kernel(ushort_t* __restrict__ xbh, ushort_t* __restrict__ xbl) {
    int i = threadIdx.x;
    #pragma unroll
    for (int k = 0; k < 8; ++k) {
        int idx = k * 256 + i;              // [0, 2048) shorts
        int chunk = idx >> 8;
        int rem = idx & 255;
        size_t o = (size_t)chunk * CHSZS + (size_t)NNODES * 32 + rem;
        xbh[o] = 0;
        xbl[o] = 0;
    }
}

// ---------------- weight prep: split + B-FRAGMENT SWIZZLE ----------------
__global__ void wprep_kernel(const float* __restrict__ e1, const float* __restrict__ e2,
                             const float* __restrict__ gi, const float* __restrict__ gl,
                             const float* __restrict__ go, const float* __restrict__ pj,
                             ushort_t* __restrict__ hi, ushort_t* __restrict__ lo) {
    int i = blockIdx.x * 256 + threadIdx.x;
    if (i >= 491520) return;
    float v;
    if (i < 131072)      v = (i < 65536) ? e1[i] : e2[i - 65536];
    else if (i < 196608) v = gi[i - 131072];
    else if (i < 393216) v = gl[i - 196608];
    else if (i < 458752) v = go[i - 393216];
    else                 v = pj[i - 458752];
    int base = (i < 458752) ? (i & ~65535) : 458752;
    int r = i - base;
    int col = r >> 8, k = r & 255;
    int ct = col >> 4, fr = col & 15;
    int c = k >> 5, fq = (k >> 3) & 3, j = k & 7;
    int o = base + (ct * 8 + c) * 512 + (fq * 16 + fr) * 8 + j;
    ushort_t h = f2bf(v);
    hi[o] = h;
    lo[o] = f2bf(v - bf2f(h));
}

// ---------------- XCD-pinned chunked spmm, bf16-hi gathers ----------------
// x stored chunk-major as bf16 hi/lo: xbh/xbl[8][CHROWS][32]. Gathers read
// ONLY xbh (64 B/row-chunk = 1 L2 line vs 2 for f32 -> halves the L2 line
// rate that caps this kernel). Self-term reads hi+lo (exact to 2^-17).
// Wave = 8 rows x 8 lanes (ushort4 = 8 B/lane); padded ELL, 8-deep ILP.
__global__ __launch_bounds__(256) void spmm_chunk_kernel(
        const ushort_t* __restrict__ xbh, const ushort_t* __restrict__ xbl,
        const ushort_t* __restrict__ ell, const int* __restrict__ cnt,
        const float* __restrict__ dinv,
        ushort_t* __restrict__ outh, ushort_t* __restrict__ outl) {
    const uint32 HM = 0xFFFF0000u;
    int bx = blockIdx.x;
    int chunk = bx & 7;
    int rb = bx >> 3;
    int t = threadIdx.x;
    int lane = t & 63, w = t >> 6;
    int rloc = lane >> 3;
    int cl = lane & 7;
    int row = rb * 32 + w * 8 + rloc;
    const ushort_t* xb = xbh + (size_t)chunk * CHSZS + (cl << 2);
    int n = cnt[row];
    int np = (n + 7) & ~7;
    const ushort_t* rell = ell + (size_t)row * ELLW;
    float a0 = 0.f, a1 = 0.f, a2 = 0.f, a3 = 0.f;
    for (int i = 0; i < np; i += 8) {
        ushort4 ja = *(const ushort4*)&rell[i];
        ushort4 jb = *(const ushort4*)&rell[i + 4];
        uint2 u0 = *(const uint2*)&xb[(size_t)ja.x * 32];
        uint2 u1 = *(const uint2*)&xb[(size_t)ja.y * 32];
        uint2 u2 = *(const uint2*)&xb[(size_t)ja.z * 32];
        uint2 u3 = *(const uint2*)&xb[(size_t)ja.w * 32];
        uint2 u4 = *(const uint2*)&xb[(size_t)jb.x * 32];
        uint2 u5 = *(const uint2*)&xb[(size_t)jb.y * 32];
        uint2 u6 = *(const uint2*)&xb[(size_t)jb.z * 32];
        uint2 u7 = *(const uint2*)&xb[(size_t)jb.w * 32];
        a0 += (__uint_as_float(u0.x << 16) + __uint_as_float(u1.x << 16)) +
              (__uint_as_float(u2.x << 16) + __uint_as_float(u3.x << 16)) +
              (__uint_as_float(u4.x << 16) + __uint_as_float(u5.x << 16)) +
              (__uint_as_float(u6.x << 16) + __uint_as_float(u7.x << 16));
        a1 += (__uint_as_float(u0.x & HM) + __uint_as_float(u1.x & HM)) +
              (__uint_as_float(u2.x & HM) + __uint_as_float(u3.x & HM)) +
              (__uint_as_float(u4.x & HM) + __uint_as_float(u5.x & HM)) +
              (__uint_as_float(u6.x & HM) + __uint_as_float(u7.x & HM));
        a2 += (__uint_as_float(u0.y << 16) + __uint_as_float(u1.y << 16)) +
              (__uint_as_float(u2.y << 16) + __uint_as_float(u3.y << 16)) +
              (__uint_as_float(u4.y << 16) + __uint_as_float(u5.y << 16)) +
              (__uint_as_float(u6.y << 16) + __uint_as_float(u7.y << 16));
        a3 += (__uint_as_float(u0.y & HM) + __uint_as_float(u1.y & HM)) +
              (__uint_as_float(u2.y & HM) + __uint_as_float(u3.y & HM)) +
              (__uint_as_float(u4.y & HM) + __uint_as_float(u5.y & HM)) +
              (__uint_as_float(u6.y & HM) + __uint_as_float(u7.y & HM));
    }
    size_t so = (size_t)chunk * CHSZS + (size_t)row * 32 + (cl << 2);
    uint2 uh = *(const uint2*)&xbh[so];
    uint2 ul = *(const uint2*)&xbl[so];
    float x0 = __uint_as_float(uh.x << 16) + __uint_as_float(ul.x << 16);
    float x1 = __uint_as_float(uh.x & HM) + __uint_as_float(ul.x & HM);
    float x2 = __uint_as_float(uh.y << 16) + __uint_as_float(ul.y << 16);
    float x3 = __uint_as_float(uh.y & HM) + __uint_as_float(ul.y & HM);
    float dv = dinv[row];
    float sx = x0 + dv * a0;
    float sy = x1 + dv * a1;
    float sz = x2 + dv * a2;
    float sw = x3 + dv * a3;
    ushort_t hx = f2bf(sx), hy = f2bf(sy), hz = f2bf(sz), hw = f2bf(sw);
    size_t o = (size_t)row * 256 + (chunk << 5) + (cl << 2);
    *(ushort4*)&outh[o] = make_ushort4(hx, hy, hz, hw);
    *(ushort4*)&outl[o] = make_ushort4(f2bf(sx - bf2f(hx)), f2bf(sy - bf2f(hy)),
                                       f2bf(sz - bf2f(hz)), f2bf(sw - bf2f(hw)));
}

// ---------------- band-GEMM machinery (frag-swizzled A in LDS, B from L2) ----
template<int NTW>
__device__ __forceinline__ void band_step(
        const ushort_t* Ah, const ushort_t* Al,
        const ushort_t* __restrict__ Wh, const ushort_t* __restrict__ Wl,
        int w, int lane, f32x4 (&acc)[2][NTW]) {
    int ct0 = w * NTW;
    short8_t bh[NTW], bl[NTW];
    #pragma unroll
    for (int nt = 0; nt < NTW; ++nt) {
        size_t bo = (size_t)((ct0 + nt) * 8) * 512 + lane * 8;
        bh[nt] = *(const short8_t*)&Wh[bo];
        bl[nt] = *(const short8_t*)&Wl[bo];
    }
    #pragma unroll
    for (int c = 0; c < 8; ++c) {
        short8_t bhn[NTW], bln[NTW];
        if (c < 7) {
            #pragma unroll
            for (int nt = 0; nt < NTW; ++nt) {
                size_t bo = (size_t)((ct0 + nt) * 8 + c + 1) * 512 + lane * 8;
                bhn[nt] = *(const short8_t*)&Wh[bo];
                bln[nt] = *(const short8_t*)&Wl[bo];
            }
        }
        short8_t ah[2], al[2];
        #pragma unroll
        for (int mt = 0; mt < 2; ++mt) {
            int ao = (c * 2 + mt) * 512 + lane * 8;
            ah[mt] = *(const short8_t*)&Ah[ao];
            al[mt] = *(const short8_t*)&Al[ao];
        }
        #pragma unroll
        for (int mt = 0; mt < 2; ++mt)
            #pragma unroll
            for (int nt = 0; nt < NTW; ++nt) {
                f32x4 a = acc[mt][nt];
                a = __builtin_amdgcn_mfma_f32_16x16x32_bf16(ah[mt], bh[nt], a, 0, 0, 0);
                a = __builtin_amdgcn_mfma_f32_16x16x32_bf16(ah[mt], bl[nt], a, 0, 0, 0);
                a = __builtin_amdgcn_mfma_f32_16x16x32_bf16(al[mt], bh[nt], a, 0, 0, 0);
                acc[mt][nt] = a;
            }
        if (c < 7) {
            #pragma unroll
            for (int nt = 0; nt < NTW; ++nt) { bh[nt] = bhn[nt]; bl[nt] = bln[nt]; }
        }
    }
}

template<int NTW>
__device__ __forceinline__ void acc_zero(f32x4 (&acc)[2][NTW]) {
    #pragma unroll
    for (int a = 0; a < 2; ++a)
        #pragma unroll
        for (int b = 0; b < NTW; ++b) {
            f32x4 z = {0.f, 0.f, 0.f, 0.f};
            acc[a][b] = z;
        }
}

// bias + optional relu, split to hi/lo, store in FRAG layout for next step
template<int NTW, bool RELU>
__device__ __forceinline__ void acc_to_lds(
        f32x4 (&acc)[2][NTW], const float* __restrict__ bias,
        int w, int lane, ushort_t* Ah, ushort_t* Al) {
    int fr = lane & 15, fq = lane >> 4;
    int col0 = w * (16 * NTW);
    #pragma unroll
    for (int mt = 0; mt < 2; ++mt)
        #pragma unroll
        for (int nt = 0; nt < NTW; ++nt) {
            int col = col0 + 16 * nt + fr;         // next-step k index
            float bb = bias[col];
            int c = col >> 5, k32 = col & 31;
            int fqn = k32 >> 3, jn = k32 & 7;
            #pragma unroll
            for (int e = 0; e < 4; ++e) {
                int r = 16 * mt + fq * 4 + e;      // 0..31
                float v = acc[mt][nt][e] + bb;
                if (RELU) v = fmaxf(v, 0.0f);
                ushort_t h = f2bf(v);
                int addr = ((c * 2) + (r >> 4)) * 512 + (fqn * 16 + (r & 15)) * 8 + jn;
                Ah[addr] = h;
                Al[addr] = f2bf(v - bf2f(h));
            }
        }
}

// stage a pre-split bf16 pair band [N][256] (row-major) into FRAG LDS
__device__ __forceinline__ void stage_pair(
        const ushort_t* __restrict__ Xh_, const ushort_t* __restrict__ Xl_,
        int row0, int tid, ushort_t* Ah, ushort_t* Al) {
    #pragma unroll
    for (int i = 0; i < 2; ++i) {
        int s = i * 512 + tid;             // 1024 short8 slots
        int r = s >> 5;                    // row 0..31
        int kq = s & 31;                   // k-octet
        short8_t vh = *(const short8_t*)&Xh_[(size_t)(row0 + r) * 256 + kq * 8];
        short8_t vl = *(const short8_t*)&Xl_[(size_t)(row0 + r) * 256 + kq * 8];
        int c = kq >> 2, fq = kq & 3;
        int addr = (c * 2 + (r >> 4)) * 512 + (fq * 16 + (r & 15)) * 8;
        *(short8_t*)&Ah[addr] = vh;
        *(short8_t*)&Al[addr] = vl;
    }
}

// ---------------- fused encoder: nf -> enc1(relu) -> enc2 -> gin(relu) -> xb ----
__global__ __launch_bounds__(512) void fused_enc_kernel(
        const float* __restrict__ nf,
        const ushort_t* __restrict__ Wh, const ushort_t* __restrict__ Wl,
        const float* __restrict__ b1, const float* __restrict__ b2,
        const float* __restrict__ b3,
        ushort_t* __restrict__ xbh, ushort_t* __restrict__ xbl) {
    __shared__ __align__(16) ushort_t Ah[8192];
    __shared__ __align__(16) ushort_t Al[8192];
    int tid = threadIdx.x;
    int lane = tid & 63;
    int w = __builtin_amdgcn_readfirstlane(tid >> 6);   // 0..7
    int row0 = blockIdx.x * 32;
    int fr = lane & 15, fq = lane >> 4;

    // stage nf band with on-the-fly hi/lo split into frag layout
    #pragma unroll
    for (int i = 0; i < 4; ++i) {
        int s = i * 512 + tid;             // 2048 float4 slots
        int r = s >> 6, k4 = s & 63;
        float4 v = *(const float4*)&nf[(size_t)(row0 + r) * 256 + k4 * 4];
        ushort_t h0 = f2bf(v.x), h1 = f2bf(v.y), h2 = f2bf(v.z), h3 = f2bf(v.w);
        int kq = k4 >> 1, half = (k4 & 1) * 4;
        int c = kq >> 2, fqs = kq & 3;
        int addr = (c * 2 + (r >> 4)) * 512 + (fqs * 16 + (r & 15)) * 8 + half;
        *(ushort4*)&Ah[addr] = make_ushort4(h0, h1, h2, h3);
        *(ushort4*)&Al[addr] =
            make_ushort4(f2bf(v.x - bf2f(h0)), f2bf(v.y - bf2f(h1)),
                         f2bf(v.z - bf2f(h2)), f2bf(v.w - bf2f(h3)));
    }
    __syncthreads();

    f32x4 acc[2][2];
    // enc1 (relu)
    acc_zero<2>(acc);
    band_step<2>(Ah, Al, Wh, Wl, w, lane, acc);
    __syncthreads();
    acc_to_lds<2, true>(acc, b1, w, lane, Ah, Al);
    __syncthreads();
    // enc2 (no relu)
    acc_zero<2>(acc);
    band_step<2>(Ah, Al, Wh + 65536, Wl + 65536, w, lane, acc);
    __syncthreads();
    acc_to_lds<2, false>(acc, b2, w, lane, Ah, Al);
    __syncthreads();
    // gin (relu) -> bf16 hi/lo chunk-major
    acc_zero<2>(acc);
    band_step<2>(Ah, Al, Wh + 131072, Wl + 131072, w, lane, acc);
    int col0 = w * 32;
    #pragma unroll
    for (int mt = 0; mt < 2; ++mt)
        #pragma unroll
        for (int nt = 0; nt < 2; ++nt) {
            int gc = col0 + 16 * nt + fr;
            float bb = b3[gc];
            #pragma unroll
            for (int e = 0; e < 4; ++e) {
                int gr = row0 + 16 * mt + fq * 4 + e;
                float v = fmaxf(acc[mt][nt][e] + bb, 0.0f);
                size_t off = (size_t)(gc >> 5) * CHSZS + (size_t)gr * 32 + (gc & 31);
                ushort_t h = f2bf(v);
                xbh[off] = h;
                xbl[off] = f2bf(v - bf2f(h));
            }
        }
}

// ---------------- gl layer band GEMM: pair -> relu -> xb bf16 or pair bf16 -----
template<bool CHUNKX>
__global__ __launch_bounds__(512) void gl_band_kernel(
        const ushort_t* __restrict__ Xh_, const ushort_t* __restrict__ Xl_,
        const ushort_t* __restrict__ Wh, const ushort_t* __restrict__ Wl,
        const float* __restrict__ bias,
        ushort_t* __restrict__ xbh, ushort_t* __restrict__ xbl,
        ushort_t* __restrict__ Yh, ushort_t* __restrict__ Yl) {
    __shared__ __align__(16) ushort_t Ah[8192];
    __shared__ __align__(16) ushort_t Al[8192];
    int tid = threadIdx.x;
    int lane = tid & 63;
    int w = __builtin_amdgcn_readfirstlane(tid >> 6);
    int row0 = blockIdx.x * 32;
    int fr = lane & 15, fq = lane >> 4;
    stage_pair(Xh_, Xl_, row0, tid, Ah, Al);
    __syncthreads();
    f32x4 acc[2][2];
    acc_zero<2>(acc);
    band_step<2>(Ah, Al, Wh, Wl, w, lane, acc);
    int col0 = w * 32;
    #pragma unroll
    for (int mt = 0; mt < 2; ++mt)
        #pragma unroll
        for (int nt = 0; nt < 2; ++nt) {
            int gc = col0 + 16 * nt + fr;
            float bb = bias[gc];
            #pragma unroll
            for (int e = 0; e < 4; ++e) {
                int gr = row0 + 16 * mt + fq * 4 + e;
                float v = fmaxf(acc[mt][nt][e] + bb, 0.0f);   // gl always relu
                ushort_t h = f2bf(v);
                ushort_t l = f2bf(v - bf2f(h));
                if (CHUNKX) {
                    size_t off = (size_t)(gc >> 5) * CHSZS + (size_t)gr * 32 + (gc & 31);
                    xbh[off] = h;
                    xbl[off] = l;
                } else {
                    size_t off = (size_t)gr * 256 + gc;
                    Yh[off] = h;
                    Yl[off] = l;
                }
            }
        }
}

// ---------------- fused output: gout -> proj(relu) -> hc1(relu) -> hc2 + mean ---
__global__ __launch_bounds__(512) void fused_out_kernel(
        const ushort_t* __restrict__ Xh_, const ushort_t* __restrict__ Xl_,
        const ushort_t* __restrict__ Wh, const ushort_t* __restrict__ Wl,
        const float* __restrict__ gout_b, const float* __restrict__ proj_b,
        const float* __restrict__ hc_w1, const float* __restrict__ hc_b1,
        const float* __restrict__ hc_w2, const float* __restrict__ hc_b2,
        float* __restrict__ ne, float* __restrict__ logits, float* __restrict__ gf) {
    __shared__ __align__(16) char arena[33792 + 16896 + 8704];
    ushort_t* Ah = (ushort_t*)arena;                    // 16 KB (MFMA phases)
    ushort_t* Al = (ushort_t*)(arena + 16384);          // 16 KB (MFMA phases)
    float* WL = (float*)arena;                          // 33792 B (hc1 phase)
    float* Pf = (float*)(arena + 33792);                // 32 x 132 f32
    float* T1 = (float*)(arena + 33792 + 16896);        // 32 x 68 f32
    int tid = threadIdx.x;
    int lane = tid & 63;
    int w = __builtin_amdgcn_readfirstlane(tid >> 6);
    int row0 = blockIdx.x * 32;
    int fr = lane & 15, fq = lane >> 4;
    stage_pair(Xh_, Xl_, row0, tid, Ah, Al);
    __syncthreads();

    // gout (no relu) -> frag LDS pair
    f32x4 acc[2][2];
    acc_zero<2>(acc);
    band_step<2>(Ah, Al, Wh + 393216, Wl + 393216, w, lane, acc);
    __syncthreads();
    acc_to_lds<2, false>(acc, gout_b, w, lane, Ah, Al);
    __syncthreads();

    // proj (relu), Mcols=128: 8 waves x 16 cols
    f32x4 acc2[2][1];
    acc_zero<1>(acc2);
    band_step<1>(Ah, Al, Wh + 458752, Wl + 458752, w, lane, acc2);
    __syncthreads();   // all Ah/Al reads done -> safe to overwrite with WL

    // write proj -> ne + Pf; concurrently stage hc_w1 -> WL (disjoint regions)
    int col0 = w * 16;
    #pragma unroll
    for (int mt = 0; mt < 2; ++mt) {
        int gc = col0 + fr;
        float bb = proj_b[gc];
        #pragma unroll
        for (int e = 0; e < 4; ++e) {
            int r = 16 * mt + fq * 4 + e;
            float v = fmaxf(acc2[mt][0][e] + bb, 0.0f);
            ne[(size_t)(row0 + r) * 128 + gc] = v;
            Pf[r * 132 + gc] = v;
        }
    }
    #pragma unroll
    for (int i = 0; i < 4; ++i) {
        int j4 = i * 512 + tid;            // 2048 float4 slots (64 x 32)
        int m = j4 >> 5, k4 = j4 & 31;
        float4 v = *(const float4*)&hc_w1[(size_t)m * 128 + k4 * 4];
        *(float4*)&WL[m * 132 + k4 * 4] = v;
    }
    __syncthreads();

    // hc1 (relu): 32 rows x 64 cols; thread = (row r, cg); col = jj*16+cg
    {
        int r = tid >> 4, cg = tid & 15;
        float a4[4];
        #pragma unroll
        for (int jj = 0; jj < 4; ++jj) a4[jj] = hc_b1[jj * 16 + cg];
        for (int k4 = 0; k4 < 32; ++k4) {
            float4 x = *(const float4*)&Pf[r * 132 + k4 * 4];
            #pragma unroll
            for (int jj = 0; jj < 4; ++jj) {
                float4 wv = *(const float4*)&WL[(jj * 16 + cg) * 132 + k4 * 4];
                a4[jj] += x.x * wv.x + x.y * wv.y + x.z * wv.z + x.w * wv.w;
            }
        }
        #pragma unroll
        for (int jj = 0; jj < 4; ++jj)
            T1[r * 68 + jj * 16 + cg] = fmaxf(a4[jj], 0.0f);
    }
    __syncthreads();

    // hc2: 32x8 logits
    if (tid < 256) {
        int r = tid >> 3, m = tid & 7;
        float s = hc_b2[m];
        #pragma unroll
        for (int k4 = 0; k4 < 16; ++k4) {
            float4 x = *(const float4*)&T1[r * 68 + k4 * 4];
            float4 wv = *(const float4*)&hc_w2[(size_t)m * 64 + k4 * 4];
            s += x.x * wv.x + x.y * wv.y + x.z * wv.z + x.w * wv.w;
        }
        logits[(size_t)(row0 + r) * 8 + m] = s;
    }

    // column-mean partial of ne band
    if (tid < 128) {
        float s = 0.0f;
        #pragma unroll 4
        for (int r = 0; r < 32; ++r) s += Pf[r * 132 + tid];
        atomicAdd(&gf[tid], s * (1.0f / (float)NNODES));
    }
}

extern "C" void kernel_launch(void* const* d_in, const int* in_sizes, int n_in,
                              void* d_out, int out_size, void* d_ws, size_t ws_size,
                              hipStream_t stream) {
    const int N = NNODES;
    const float* nf     = (const float*)d_in[0];
    const int*   ei     = (const int*)d_in[1];
    const float* enc_w1 = (const float*)d_in[2];
    const float* enc_b1 = (const float*)d_in[3];
    const float* enc_w2 = (const float*)d_in[4];
    const float* enc_b2 = (const float*)d_in[5];
    const float* gin_w  = (const float*)d_in[6];
    const float* gin_b  = (const float*)d_in[7];
    const float* gl_w   = (const float*)d_in[8];
    const float* gl_b   = (const float*)d_in[9];
    const float* gout_w = (const float*)d_in[10];
    const float* gout_b = (const float*)d_in[11];
    const float* proj_w = (const float*)d_in[12];
    const float* proj_b = (const float*)d_in[13];
    const float* hc_w1  = (const float*)d_in[14];
    const float* hc_b1  = (const float*)d_in[15];
    const float* hc_w2  = (const float*)d_in[16];
    const float* hc_b2  = (const float*)d_in[17];
    const int E = in_sizes[1] >> 1;

    // workspace carve (bytes):
    // [0, 37748736): masks M+MT -- dead after ell_fill; then aliased by
    //   xbh/xbl (bf16 chunk-major, 2 x 6,295,552) + pairA/pairB hi/lo
    char* ws = (char*)d_ws;
    u64* M  = (u64*)ws;
    u64* MT = M + (size_t)N * WORDS;
    ushort_t* xbh = (ushort_t*)ws;                              //  6,295,552
    ushort_t* xbl = (ushort_t*)(ws + 6295552);                  //  6,295,552
    ushort_t* pAh = (ushort_t*)(ws + 12591104);                 //  6,291,456
    ushort_t* pAl = (ushort_t*)(ws + 18882560);
    ushort_t* pBh = (ushort_t*)(ws + 25174016);
    ushort_t* pBl = (ushort_t*)(ws + 31465472);                 // ends 37,756,928
    ushort_t* ell = (ushort_t*)(ws + 37756928);                 //  6,291,456
    int*      cntb = (int*)(ws + 44048384);
    float*    dinv = (float*)(ws + 44097536);
    ushort_t* Whi  = (ushort_t*)(ws + 44146688);                //    983,040
    ushort_t* Wlo  = (ushort_t*)(ws + 45129728);                //    983,040

    float* ne     = (float*)d_out;                        // [N,128]
    float* logits = ne + (size_t)N * 128;                 // [N,8]
    float* gf     = logits + (size_t)N * 8;               // [128]

    hipMemsetAsync(M, 0, 2 * (size_t)N * WORDS * sizeof(u64), stream);
    hipMemsetAsync(gf, 0, 128 * sizeof(float), stream);

    build_mask_kernel<<<(E + 255) / 256, 256, 0, stream>>>(ei, M, MT, E);
    ell_fill_kernel<<<N / 4, 256, 0, stream>>>(M, MT, ell, cntb, dinv);
    // masks dead from here; xbh/xbl/pairs may clobber them
    clear_pad_kernel<<<1, 256, 0, stream>>>(xbh, xbl);
    wprep_kernel<<<1920, 256, 0, stream>>>(enc_w1, enc_w2, gin_w, gl_w, gout_w, proj_w,
                                           Whi, Wlo);

    const int GB = N / 32;   // 384 band blocks (512 threads / 8 waves each)
    // encoder chain fused: nf -> xb
    fused_enc_kernel<<<GB, 512, 0, stream>>>(nf, Whi, Wlo, enc_b1, enc_b2, gin_b,
                                             xbh, xbl);

    for (int i = 0; i < 3; ++i) {
        spmm_chunk_kernel<<<(N / 32) * 8, 256, 0, stream>>>(xbh, xbl, ell, cntb, dinv,
                                                            pAh, pAl);
        if (i < 2) {
            gl_band_kernel<true><<<GB, 512, 0, stream>>>(
                pAh, pAl, Whi + 196608 + 65536 * i, Wlo + 196608 + 65536 * i,
                gl_b + 256 * i, xbh, xbl, nullptr, nullptr);
        } else {
            gl_band_kernel<false><<<GB, 512, 0, stream>>>(
                pAh, pAl, Whi + 196608 + 65536 * i, Wlo + 196608 + 65536 * i,
                gl_b + 256 * i, nullptr, nullptr, pBh, pBl);
        }
    }
    // output chain fused: pB -> ne, logits, gf
    fused_out_kernel<<<GB, 512, 0, stream>>>(
        pBh, pBl, Whi, Wlo, gout_b, proj_b, hc_w1, hc_b1, hc_w2, hc_b2,
        ne, logits, gf);
}

// Round 14
// 337.472 us; speedup vs baseline: 1.0565x; 1.0565x over previous
//
#include <hip/hip_runtime.h>

typedef unsigned long long u64;
typedef unsigned short ushort_t;
typedef unsigned int uint32;

#define NNODES 12288
#define WORDS 192    // 12288 / 64 bits per row
#define ELLW 256     // max neighbors per row (avg ~64)
#define ZROW NNODES  // zeroed pad row index
#define CHROWS (NNODES + 8)          // rows per chunk incl. pad
#define CHSZS (CHROWS * 32)          // SHORTS per 32-col bf16 chunk (8 chunks)

typedef __attribute__((ext_vector_type(8))) short short8_t;   // 8 bf16 (4 VGPRs)
typedef __attribute__((ext_vector_type(4))) float f32x4;      // MFMA C/D frag

// ---- bf16 split helpers (RNE) ----
__device__ __forceinline__ ushort_t f2bf(float f) {
    uint32 u = __float_as_uint(f);
    return (ushort_t)((u + 0x7fffu + ((u >> 16) & 1u)) >> 16);
}
__device__ __forceinline__ float bf2f(ushort_t h) {
    return __uint_as_float(((uint32)h) << 16);
}

// ---------------- adjacency build: bitmask M[s][d], MT[d][s] ----------------
__global__ void build_mask_kernel(const int* __restrict__ ei, u64* __restrict__ M,
                                  u64* __restrict__ MT, int E) {
    int e = blockIdx.x * blockDim.x + threadIdx.x;
    if (e >= E) return;
    int s = ei[e];
    int d = ei[E + e];
    atomicOr(&M[(size_t)s * WORDS + (d >> 6)], 1ull << (d & 63));
    atomicOr(&MT[(size_t)d * WORDS + (s >> 6)], 1ull << (s & 63));
}

// ---------------- bitmask -> u16 ELL (padded to x8 with ZROW) ----------------
__global__ __launch_bounds__(256) void ell_fill_kernel(
        const u64* __restrict__ M, const u64* __restrict__ MT,
        ushort_t* __restrict__ ell, int* __restrict__ cnt, float* __restrict__ dinv) {
    int row = blockIdx.x * 4 + (threadIdx.x >> 6);
    int lane = threadIdx.x & 63;
    const u64* rM  = M  + (size_t)row * WORDS;
    const u64* rMT = MT + (size_t)row * WORDS;
    u64 wm[3], wt[3];
    int pm = 0, pt = 0;
    #pragma unroll
    for (int k = 0; k < 3; ++k) {
        wm[k] = rM[lane + 64 * k];  pm += __popcll(wm[k]);
        wt[k] = rMT[lane + 64 * k]; pt += __popcll(wt[k]);
    }
    int inclM = pm, inclT = pt;
    #pragma unroll
    for (int off = 1; off < 64; off <<= 1) {
        int ym = __shfl_up(inclM, off, 64);
        int yt = __shfl_up(inclT, off, 64);
        if (lane >= off) { inclM += ym; inclT += yt; }
    }
    int exclM = inclM - pm;
    int exclT = inclT - pt;
    int totM = __shfl(inclM, 63, 64);
    int totT = __shfl(inclT, 63, 64);
    ushort_t* out = ell + (size_t)row * ELLW;
    int pos = exclM;
    #pragma unroll
    for (int k = 0; k < 3; ++k) {
        u64 bits = wm[k];
        int base = (lane + 64 * k) << 6;
        while (bits) { out[pos++] = (ushort_t)(base + __builtin_ctzll(bits)); bits &= bits - 1; }
    }
    pos = totM + exclT;
    #pragma unroll
    for (int k = 0; k < 3; ++k) {
        u64 bits = wt[k];
        int base = (lane + 64 * k) << 6;
        while (bits) { out[pos++] = (ushort_t)(base + __builtin_ctzll(bits)); bits &= bits - 1; }
    }
    if (lane == 0) {
        int n = totM + totT;
        int np = (n + 7) & ~7;
        for (int p = n; p < np; ++p) out[p] = (ushort_t)ZROW;
        cnt[row] = n;
        dinv[row] = 1.0f / ((float)n + 1e-8f);
    }
}

// zero the 8 pad rows of each of the 8 chunks (bf16 hi and lo arrays)
__global__ void clear_pad_kernel(ushort_t* __restrict__ xbh, ushort_t* __restrict__ xbl) {
    int i = threadIdx.x;
    #pragma unroll
    for (int k = 0; k < 8; ++k) {
        int idx = k * 256 + i;              // [0, 2048) shorts
        int chunk = idx >> 8;
        int rem = idx & 255;
        size_t o = (size_t)chunk * CHSZS + (size_t)NNODES * 32 + rem;
        xbh[o] = 0;
        xbl[o] = 0;
    }
}

// ---------------- weight prep: split + B-FRAGMENT SWIZZLE ----------------
__global__ void wprep_kernel(const float* __restrict__ e1, const float* __restrict__ e2,
                             const float* __restrict__ gi, const float* __restrict__ gl,
                             const float* __restrict__ go, const float* __restrict__ pj,
                             ushort_t* __restrict__ hi, ushort_t* __restrict__ lo) {
    int i = blockIdx.x * 256 + threadIdx.x;
    if (i >= 491520) return;
    float v;
    if (i < 131072)      v = (i < 65536) ? e1[i] : e2[i - 65536];
    else if (i < 196608) v = gi[i - 131072];
    else if (i < 393216) v = gl[i - 196608];
    else if (i < 458752) v = go[i - 393216];
    else                 v = pj[i - 458752];
    int base = (i < 458752) ? (i & ~65535) : 458752;
    int r = i - base;
    int col = r >> 8, k = r & 255;
    int ct = col >> 4, fr = col & 15;
    int c = k >> 5, fq = (k >> 3) & 3, j = k & 7;
    int o = base + (ct * 8 + c) * 512 + (fq * 16 + fr) * 8 + j;
    ushort_t h = f2bf(v);
    hi[o] = h;
    lo[o] = f2bf(v - bf2f(h));
}

// ---------------- XCD-pinned chunked spmm, 16B-per-lane bf16 gathers ---------
// Wave = 16 rows x 4 lanes x ushort8 (16 B): a 64 B row-chunk gather costs 4
// lane-addresses instead of 8 -> total L1-lookup/address work halves (rounds
// 8/13 showed time invariant to bytes and L2 lines; addresses are the
// remaining invariant that matches the measured 30 cyc/instr).
__device__ __forceinline__ void acc_u4(uint4 u, float* a) {
    const uint32 HM = 0xFFFF0000u;
    a[0] += __uint_as_float(u.x << 16);
    a[1] += __uint_as_float(u.x & HM);
    a[2] += __uint_as_float(u.y << 16);
    a[3] += __uint_as_float(u.y & HM);
    a[4] += __uint_as_float(u.z << 16);
    a[5] += __uint_as_float(u.z & HM);
    a[6] += __uint_as_float(u.w << 16);
    a[7] += __uint_as_float(u.w & HM);
}

__global__ __launch_bounds__(256) void spmm_chunk_kernel(
        const ushort_t* __restrict__ xbh, const ushort_t* __restrict__ xbl,
        const ushort_t* __restrict__ ell, const int* __restrict__ cnt,
        const float* __restrict__ dinv,
        ushort_t* __restrict__ outh, ushort_t* __restrict__ outl) {
    const uint32 HM = 0xFFFF0000u;
    int bx = blockIdx.x;
    int chunk = bx & 7;
    int rb = bx >> 3;                  // 0..191, 64 rows each
    int t = threadIdx.x;
    int lane = t & 63, w = t >> 6;
    int rloc = lane >> 2;              // 0..15
    int cl = lane & 3;                 // ushort8 group within 32-col chunk
    int row = rb * 64 + w * 16 + rloc;
    const ushort_t* xb = xbh + (size_t)chunk * CHSZS + (cl << 3);
    int n = cnt[row];
    int np = (n + 7) & ~7;
    const ushort_t* rell = ell + (size_t)row * ELLW;
    float a[8] = {};
    for (int i = 0; i < np; i += 8) {
        ushort4 ja = *(const ushort4*)&rell[i];
        ushort4 jb = *(const ushort4*)&rell[i + 4];
        uint4 u0 = *(const uint4*)&xb[(size_t)ja.x * 32];
        uint4 u1 = *(const uint4*)&xb[(size_t)ja.y * 32];
        uint4 u2 = *(const uint4*)&xb[(size_t)ja.z * 32];
        uint4 u3 = *(const uint4*)&xb[(size_t)ja.w * 32];
        uint4 u4 = *(const uint4*)&xb[(size_t)jb.x * 32];
        uint4 u5 = *(const uint4*)&xb[(size_t)jb.y * 32];
        uint4 u6 = *(const uint4*)&xb[(size_t)jb.z * 32];
        uint4 u7 = *(const uint4*)&xb[(size_t)jb.w * 32];
        acc_u4(u0, a); acc_u4(u1, a); acc_u4(u2, a); acc_u4(u3, a);
        acc_u4(u4, a); acc_u4(u5, a); acc_u4(u6, a); acc_u4(u7, a);
    }
    size_t so = (size_t)chunk * CHSZS + (size_t)row * 32 + (cl << 3);
    uint4 uh = *(const uint4*)&xbh[so];
    uint4 ul = *(const uint4*)&xbl[so];
    uint32 hu[4] = {uh.x, uh.y, uh.z, uh.w};
    uint32 lu[4] = {ul.x, ul.y, ul.z, ul.w};
    float dv = dinv[row];
    short8_t vh, vl;
    #pragma unroll
    for (int q = 0; q < 4; ++q) {
        float xlo = __uint_as_float(hu[q] << 16) + __uint_as_float(lu[q] << 16);
        float xhi = __uint_as_float(hu[q] & HM) + __uint_as_float(lu[q] & HM);
        float s0 = xlo + dv * a[2 * q];
        float s1 = xhi + dv * a[2 * q + 1];
        ushort_t h0 = f2bf(s0), h1 = f2bf(s1);
        vh[2 * q] = (short)h0;
        vh[2 * q + 1] = (short)h1;
        vl[2 * q] = (short)f2bf(s0 - bf2f(h0));
        vl[2 * q + 1] = (short)f2bf(s1 - bf2f(h1));
    }
    size_t o = (size_t)row * 256 + (chunk << 5) + (cl << 3);
    *(short8_t*)&outh[o] = vh;
    *(short8_t*)&outl[o] = vl;
}

// ---------------- band-GEMM machinery (frag-swizzled A in LDS, B from L2) ----
template<int NTW>
__device__ __forceinline__ void band_step(
        const ushort_t* Ah, const ushort_t* Al,
        const ushort_t* __restrict__ Wh, const ushort_t* __restrict__ Wl,
        int w, int lane, f32x4 (&acc)[2][NTW]) {
    int ct0 = w * NTW;
    short8_t bh[NTW], bl[NTW];
    #pragma unroll
    for (int nt = 0; nt < NTW; ++nt) {
        size_t bo = (size_t)((ct0 + nt) * 8) * 512 + lane * 8;
        bh[nt] = *(const short8_t*)&Wh[bo];
        bl[nt] = *(const short8_t*)&Wl[bo];
    }
    #pragma unroll
    for (int c = 0; c < 8; ++c) {
        short8_t bhn[NTW], bln[NTW];
        if (c < 7) {
            #pragma unroll
            for (int nt = 0; nt < NTW; ++nt) {
                size_t bo = (size_t)((ct0 + nt) * 8 + c + 1) * 512 + lane * 8;
                bhn[nt] = *(const short8_t*)&Wh[bo];
                bln[nt] = *(const short8_t*)&Wl[bo];
            }
        }
        short8_t ah[2], al[2];
        #pragma unroll
        for (int mt = 0; mt < 2; ++mt) {
            int ao = (c * 2 + mt) * 512 + lane * 8;
            ah[mt] = *(const short8_t*)&Ah[ao];
            al[mt] = *(const short8_t*)&Al[ao];
        }
        #pragma unroll
        for (int mt = 0; mt < 2; ++mt)
            #pragma unroll
            for (int nt = 0; nt < NTW; ++nt) {
                f32x4 a = acc[mt][nt];
                a = __builtin_amdgcn_mfma_f32_16x16x32_bf16(ah[mt], bh[nt], a, 0, 0, 0);
                a = __builtin_amdgcn_mfma_f32_16x16x32_bf16(ah[mt], bl[nt], a, 0, 0, 0);
                a = __builtin_amdgcn_mfma_f32_16x16x32_bf16(al[mt], bh[nt], a, 0, 0, 0);
                acc[mt][nt] = a;
            }
        if (c < 7) {
            #pragma unroll
            for (int nt = 0; nt < NTW; ++nt) { bh[nt] = bhn[nt]; bl[nt] = bln[nt]; }
        }
    }
}

template<int NTW>
__device__ __forceinline__ void acc_zero(f32x4 (&acc)[2][NTW]) {
    #pragma unroll
    for (int a = 0; a < 2; ++a)
        #pragma unroll
        for (int b = 0; b < NTW; ++b) {
            f32x4 z = {0.f, 0.f, 0.f, 0.f};
            acc[a][b] = z;
        }
}

// bias + optional relu, split to hi/lo, store in FRAG layout for next step
template<int NTW, bool RELU>
__device__ __forceinline__ void acc_to_lds(
        f32x4 (&acc)[2][NTW], const float* __restrict__ bias,
        int w, int lane, ushort_t* Ah, ushort_t* Al) {
    int fr = lane & 15, fq = lane >> 4;
    int col0 = w * (16 * NTW);
    #pragma unroll
    for (int mt = 0; mt < 2; ++mt)
        #pragma unroll
        for (int nt = 0; nt < NTW; ++nt) {
            int col = col0 + 16 * nt + fr;         // next-step k index
            float bb = bias[col];
            int c = col >> 5, k32 = col & 31;
            int fqn = k32 >> 3, jn = k32 & 7;
            #pragma unroll
            for (int e = 0; e < 4; ++e) {
                int r = 16 * mt + fq * 4 + e;      // 0..31
                float v = acc[mt][nt][e] + bb;
                if (RELU) v = fmaxf(v, 0.0f);
                ushort_t h = f2bf(v);
                int addr = ((c * 2) + (r >> 4)) * 512 + (fqn * 16 + (r & 15)) * 8 + jn;
                Ah[addr] = h;
                Al[addr] = f2bf(v - bf2f(h));
            }
        }
}

// stage a pre-split bf16 pair band [N][256] (row-major) into FRAG LDS
__device__ __forceinline__ void stage_pair(
        const ushort_t* __restrict__ Xh_, const ushort_t* __restrict__ Xl_,
        int row0, int tid, ushort_t* Ah, ushort_t* Al) {
    #pragma unroll
    for (int i = 0; i < 2; ++i) {
        int s = i * 512 + tid;             // 1024 short8 slots
        int r = s >> 5;                    // row 0..31
        int kq = s & 31;                   // k-octet
        short8_t vh = *(const short8_t*)&Xh_[(size_t)(row0 + r) * 256 + kq * 8];
        short8_t vl = *(const short8_t*)&Xl_[(size_t)(row0 + r) * 256 + kq * 8];
        int c = kq >> 2, fq = kq & 3;
        int addr = (c * 2 + (r >> 4)) * 512 + (fq * 16 + (r & 15)) * 8;
        *(short8_t*)&Ah[addr] = vh;
        *(short8_t*)&Al[addr] = vl;
    }
}

// ---------------- fused encoder: nf -> enc1(relu) -> enc2 -> gin(relu) -> xb ----
__global__ __launch_bounds__(512) void fused_enc_kernel(
        const float* __restrict__ nf,
        const ushort_t* __restrict__ Wh, const ushort_t* __restrict__ Wl,
        const float* __restrict__ b1, const float* __restrict__ b2,
        const float* __restrict__ b3,
        ushort_t* __restrict__ xbh, ushort_t* __restrict__ xbl) {
    __shared__ __align__(16) ushort_t Ah[8192];
    __shared__ __align__(16) ushort_t Al[8192];
    int tid = threadIdx.x;
    int lane = tid & 63;
    int w = __builtin_amdgcn_readfirstlane(tid >> 6);   // 0..7
    int row0 = blockIdx.x * 32;
    int fr = lane & 15, fq = lane >> 4;

    // stage nf band with on-the-fly hi/lo split into frag layout
    #pragma unroll
    for (int i = 0; i < 4; ++i) {
        int s = i * 512 + tid;             // 2048 float4 slots
        int r = s >> 6, k4 = s & 63;
        float4 v = *(const float4*)&nf[(size_t)(row0 + r) * 256 + k4 * 4];
        ushort_t h0 = f2bf(v.x), h1 = f2bf(v.y), h2 = f2bf(v.z), h3 = f2bf(v.w);
        int kq = k4 >> 1, half = (k4 & 1) * 4;
        int c = kq >> 2, fqs = kq & 3;
        int addr = (c * 2 + (r >> 4)) * 512 + (fqs * 16 + (r & 15)) * 8 + half;
        *(ushort4*)&Ah[addr] = make_ushort4(h0, h1, h2, h3);
        *(ushort4*)&Al[addr] =
            make_ushort4(f2bf(v.x - bf2f(h0)), f2bf(v.y - bf2f(h1)),
                         f2bf(v.z - bf2f(h2)), f2bf(v.w - bf2f(h3)));
    }
    __syncthreads();

    f32x4 acc[2][2];
    // enc1 (relu)
    acc_zero<2>(acc);
    band_step<2>(Ah, Al, Wh, Wl, w, lane, acc);
    __syncthreads();
    acc_to_lds<2, true>(acc, b1, w, lane, Ah, Al);
    __syncthreads();
    // enc2 (no relu)
    acc_zero<2>(acc);
    band_step<2>(Ah, Al, Wh + 65536, Wl + 65536, w, lane, acc);
    __syncthreads();
    acc_to_lds<2, false>(acc, b2, w, lane, Ah, Al);
    __syncthreads();
    // gin (relu) -> bf16 hi/lo chunk-major
    acc_zero<2>(acc);
    band_step<2>(Ah, Al, Wh + 131072, Wl + 131072, w, lane, acc);
    int col0 = w * 32;
    #pragma unroll
    for (int mt = 0; mt < 2; ++mt)
        #pragma unroll
        for (int nt = 0; nt < 2; ++nt) {
            int gc = col0 + 16 * nt + fr;
            float bb = b3[gc];
            #pragma unroll
            for (int e = 0; e < 4; ++e) {
                int gr = row0 + 16 * mt + fq * 4 + e;
                float v = fmaxf(acc[mt][nt][e] + bb, 0.0f);
                size_t off = (size_t)(gc >> 5) * CHSZS + (size_t)gr * 32 + (gc & 31);
                ushort_t h = f2bf(v);
                xbh[off] = h;
                xbl[off] = f2bf(v - bf2f(h));
            }
        }
}

// ---------------- gl layer band GEMM: pair -> relu -> xb bf16 or pair bf16 -----
template<bool CHUNKX>
__global__ __launch_bounds__(512) void gl_band_kernel(
        const ushort_t* __restrict__ Xh_, const ushort_t* __restrict__ Xl_,
        const ushort_t* __restrict__ Wh, const ushort_t* __restrict__ Wl,
        const float* __restrict__ bias,
        ushort_t* __restrict__ xbh, ushort_t* __restrict__ xbl,
        ushort_t* __restrict__ Yh, ushort_t* __restrict__ Yl) {
    __shared__ __align__(16) ushort_t Ah[8192];
    __shared__ __align__(16) ushort_t Al[8192];
    int tid = threadIdx.x;
    int lane = tid & 63;
    int w = __builtin_amdgcn_readfirstlane(tid >> 6);
    int row0 = blockIdx.x * 32;
    int fr = lane & 15, fq = lane >> 4;
    stage_pair(Xh_, Xl_, row0, tid, Ah, Al);
    __syncthreads();
    f32x4 acc[2][2];
    acc_zero<2>(acc);
    band_step<2>(Ah, Al, Wh, Wl, w, lane, acc);
    int col0 = w * 32;
    #pragma unroll
    for (int mt = 0; mt < 2; ++mt)
        #pragma unroll
        for (int nt = 0; nt < 2; ++nt) {
            int gc = col0 + 16 * nt + fr;
            float bb = bias[gc];
            #pragma unroll
            for (int e = 0; e < 4; ++e) {
                int gr = row0 + 16 * mt + fq * 4 + e;
                float v = fmaxf(acc[mt][nt][e] + bb, 0.0f);   // gl always relu
                ushort_t h = f2bf(v);
                ushort_t l = f2bf(v - bf2f(h));
                if (CHUNKX) {
                    size_t off = (size_t)(gc >> 5) * CHSZS + (size_t)gr * 32 + (gc & 31);
                    xbh[off] = h;
                    xbl[off] = l;
                } else {
                    size_t off = (size_t)gr * 256 + gc;
                    Yh[off] = h;
                    Yl[off] = l;
                }
            }
        }
}

// ---------------- fused output: gout -> proj(relu) -> hc1(relu) -> hc2 + mean ---
__global__ __launch_bounds__(512) void fused_out_kernel(
        const ushort_t* __restrict__ Xh_, const ushort_t* __restrict__ Xl_,
        const ushort_t* __restrict__ Wh, const ushort_t* __restrict__ Wl,
        const float* __restrict__ gout_b, const float* __restrict__ proj_b,
        const float* __restrict__ hc_w1, const float* __restrict__ hc_b1,
        const float* __restrict__ hc_w2, const float* __restrict__ hc_b2,
        float* __restrict__ ne, float* __restrict__ logits, float* __restrict__ gf) {
    __shared__ __align__(16) char arena[33792 + 16896 + 8704];
    ushort_t* Ah = (ushort_t*)arena;                    // 16 KB (MFMA phases)
    ushort_t* Al = (ushort_t*)(arena + 16384);          // 16 KB (MFMA phases)
    float* WL = (float*)arena;                          // 33792 B (hc1 phase)
    float* Pf = (float*)(arena + 33792);                // 32 x 132 f32
    float* T1 = (float*)(arena + 33792 + 16896);        // 32 x 68 f32
    int tid = threadIdx.x;
    int lane = tid & 63;
    int w = __builtin_amdgcn_readfirstlane(tid >> 6);
    int row0 = blockIdx.x * 32;
    int fr = lane & 15, fq = lane >> 4;
    stage_pair(Xh_, Xl_, row0, tid, Ah, Al);
    __syncthreads();

    // gout (no relu) -> frag LDS pair
    f32x4 acc[2][2];
    acc_zero<2>(acc);
    band_step<2>(Ah, Al, Wh + 393216, Wl + 393216, w, lane, acc);
    __syncthreads();
    acc_to_lds<2, false>(acc, gout_b, w, lane, Ah, Al);
    __syncthreads();

    // proj (relu), Mcols=128: 8 waves x 16 cols
    f32x4 acc2[2][1];
    acc_zero<1>(acc2);
    band_step<1>(Ah, Al, Wh + 458752, Wl + 458752, w, lane, acc2);
    __syncthreads();   // all Ah/Al reads done -> safe to overwrite with WL

    // write proj -> ne + Pf; concurrently stage hc_w1 -> WL (disjoint regions)
    int col0 = w * 16;
    #pragma unroll
    for (int mt = 0; mt < 2; ++mt) {
        int gc = col0 + fr;
        float bb = proj_b[gc];
        #pragma unroll
        for (int e = 0; e < 4; ++e) {
            int r = 16 * mt + fq * 4 + e;
            float v = fmaxf(acc2[mt][0][e] + bb, 0.0f);
            ne[(size_t)(row0 + r) * 128 + gc] = v;
            Pf[r * 132 + gc] = v;
        }
    }
    #pragma unroll
    for (int i = 0; i < 4; ++i) {
        int j4 = i * 512 + tid;            // 2048 float4 slots (64 x 32)
        int m = j4 >> 5, k4 = j4 & 31;
        float4 v = *(const float4*)&hc_w1[(size_t)m * 128 + k4 * 4];
        *(float4*)&WL[m * 132 + k4 * 4] = v;
    }
    __syncthreads();

    // hc1 (relu): 32 rows x 64 cols; thread = (row r, cg); col = jj*16+cg
    {
        int r = tid >> 4, cg = tid & 15;
        float a4[4];
        #pragma unroll
        for (int jj = 0; jj < 4; ++jj) a4[jj] = hc_b1[jj * 16 + cg];
        for (int k4 = 0; k4 < 32; ++k4) {
            float4 x = *(const float4*)&Pf[r * 132 + k4 * 4];
            #pragma unroll
            for (int jj = 0; jj < 4; ++jj) {
                float4 wv = *(const float4*)&WL[(jj * 16 + cg) * 132 + k4 * 4];
                a4[jj] += x.x * wv.x + x.y * wv.y + x.z * wv.z + x.w * wv.w;
            }
        }
        #pragma unroll
        for (int jj = 0; jj < 4; ++jj)
            T1[r * 68 + jj * 16 + cg] = fmaxf(a4[jj], 0.0f);
    }
    __syncthreads();

    // hc2: 32x8 logits
    if (tid < 256) {
        int r = tid >> 3, m = tid & 7;
        float s = hc_b2[m];
        #pragma unroll
        for (int k4 = 0; k4 < 16; ++k4) {
            float4 x = *(const float4*)&T1[r * 68 + k4 * 4];
            float4 wv = *(const float4*)&hc_w2[(size_t)m * 64 + k4 * 4];
            s += x.x * wv.x + x.y * wv.y + x.z * wv.z + x.w * wv.w;
        }
        logits[(size_t)(row0 + r) * 8 + m] = s;
    }

    // column-mean partial of ne band
    if (tid < 128) {
        float s = 0.0f;
        #pragma unroll 4
        for (int r = 0; r < 32; ++r) s += Pf[r * 132 + tid];
        atomicAdd(&gf[tid], s * (1.0f / (float)NNODES));
    }
}

extern "C" void kernel_launch(void* const* d_in, const int* in_sizes, int n_in,
                              void* d_out, int out_size, void* d_ws, size_t ws_size,
                              hipStream_t stream) {
    const int N = NNODES;
    const float* nf     = (const float*)d_in[0];
    const int*   ei     = (const int*)d_in[1];
    const float* enc_w1 = (const float*)d_in[2];
    const float* enc_b1 = (const float*)d_in[3];
    const float* enc_w2 = (const float*)d_in[4];
    const float* enc_b2 = (const float*)d_in[5];
    const float* gin_w  = (const float*)d_in[6];
    const float* gin_b  = (const float*)d_in[7];
    const float* gl_w   = (const float*)d_in[8];
    const float* gl_b   = (const float*)d_in[9];
    const float* gout_w = (const float*)d_in[10];
    const float* gout_b = (const float*)d_in[11];
    const float* proj_w = (const float*)d_in[12];
    const float* proj_b = (const float*)d_in[13];
    const float* hc_w1  = (const float*)d_in[14];
    const float* hc_b1  = (const float*)d_in[15];
    const float* hc_w2  = (const float*)d_in[16];
    const float* hc_b2  = (const float*)d_in[17];
    const int E = in_sizes[1] >> 1;

    // workspace carve (bytes):
    // [0, 37748736): masks M+MT -- dead after ell_fill; then aliased by
    //   xbh/xbl (bf16 chunk-major, 2 x 6,295,552) + pairA/pairB hi/lo
    char* ws = (char*)d_ws;
    u64* M  = (u64*)ws;
    u64* MT = M + (size_t)N * WORDS;
    ushort_t* xbh = (ushort_t*)ws;                              //  6,295,552
    ushort_t* xbl = (ushort_t*)(ws + 6295552);                  //  6,295,552
    ushort_t* pAh = (ushort_t*)(ws + 12591104);                 //  6,291,456
    ushort_t* pAl = (ushort_t*)(ws + 18882560);
    ushort_t* pBh = (ushort_t*)(ws + 25174016);
    ushort_t* pBl = (ushort_t*)(ws + 31465472);                 // ends 37,756,928
    ushort_t* ell = (ushort_t*)(ws + 37756928);                 //  6,291,456
    int*      cntb = (int*)(ws + 44048384);
    float*    dinv = (float*)(ws + 44097536);
    ushort_t* Whi  = (ushort_t*)(ws + 44146688);                //    983,040
    ushort_t* Wlo  = (ushort_t*)(ws + 45129728);                //    983,040

    float* ne     = (float*)d_out;                        // [N,128]
    float* logits = ne + (size_t)N * 128;                 // [N,8]
    float* gf     = logits + (size_t)N * 8;               // [128]

    hipMemsetAsync(M, 0, 2 * (size_t)N * WORDS * sizeof(u64), stream);
    hipMemsetAsync(gf, 0, 128 * sizeof(float), stream);

    build_mask_kernel<<<(E + 255) / 256, 256, 0, stream>>>(ei, M, MT, E);
    ell_fill_kernel<<<N / 4, 256, 0, stream>>>(M, MT, ell, cntb, dinv);
    // masks dead from here; xbh/xbl/pairs may clobber them
    clear_pad_kernel<<<1, 256, 0, stream>>>(xbh, xbl);
    wprep_kernel<<<1920, 256, 0, stream>>>(enc_w1, enc_w2, gin_w, gl_w, gout_w, proj_w,
                                           Whi, Wlo);

    const int GB = N / 32;   // 384 band blocks (512 threads / 8 waves each)
    // encoder chain fused: nf -> xb
    fused_enc_kernel<<<GB, 512, 0, stream>>>(nf, Whi, Wlo, enc_b1, enc_b2, gin_b,
                                             xbh, xbl);

    for (int i = 0; i < 3; ++i) {
        spmm_chunk_kernel<<<(N / 64) * 8, 256, 0, stream>>>(xbh, xbl, ell, cntb, dinv,
                                                            pAh, pAl);
        if (i < 2) {
            gl_band_kernel<true><<<GB, 512, 0, stream>>>(
                pAh, pAl, Whi + 196608 + 65536 * i, Wlo + 196608 + 65536 * i,
                gl_b + 256 * i, xbh, xbl, nullptr, nullptr);
        } else {
            gl_band_kernel<false><<<GB, 512, 0, stream>>>(
                pAh, pAl, Whi + 196608 + 65536 * i, Wlo + 196608 + 65536 * i,
                gl_b + 256 * i, nullptr, nullptr, pBh, pBl);
        }
    }
    // output chain fused: pB -> ne, logits, gf
    fused_out_kernel<<<GB, 512, 0, stream>>>(
        pBh, pBl, Whi, Wlo, gout_b, proj_b, hc_w1, hc_b1, hc_w2, hc_b2,
        ne, logits, gf);
}